// Round 11
// baseline (497.458 us; speedup 1.0000x reference)
//
#include <hip/hip_runtime.h>
#include <math.h>
#include <float.h>

#define HN 256
#define DN 512
#define CCLS 1000
#define BB 16
#define SS 1024
#define NSTEPS 8
#define G4 1024   // 4*H
#define KV 768    // s(256) + ctx(512)

using f16x8 = __attribute__((ext_vector_type(8))) _Float16;
using f32x4 = __attribute__((ext_vector_type(4))) float;

__device__ __forceinline__ void gload_lds16(const void* g, void* l) {
    __builtin_amdgcn_global_load_lds((const __attribute__((address_space(1))) void*)g,
                                     (__attribute__((address_space(3))) void*)l, 16, 0, 0);
}

// NaN-safe fast tanh: 1 - 2/(e^{2x}+1)
__device__ __forceinline__ float ftanh(float x) {
    float e = __expf(2.f * x);
    return 1.f - 2.f / (e + 1.f);
}
__device__ __forceinline__ float fsigm(float x) {
    return 1.f / (1.f + __expf(-x));
}

// ================= prep: conv_enc (0..4095) | convW (4096..4607) | transAll (4608..6079)
//                   | init (6080..6239) | vnorm (6240) =================
__global__ __launch_bounds__(256) void prep_k(const float* __restrict__ enc,
                                              const float* __restrict__ W1, const float* __restrict__ W2,
                                              const float* __restrict__ Lss, const float* __restrict__ Lgs,
                                              const float* __restrict__ Lsy, const float* __restrict__ Lgy,
                                              const float* __restrict__ Wsm, const float* __restrict__ Wsc,
                                              const float* __restrict__ Lyy,
                                              const float* __restrict__ vM, const float* __restrict__ g,
                                              const float* __restrict__ Wsmb, const float* __restrict__ Wscb,
                                              _Float16* __restrict__ A16, _Float16* __restrict__ WcT,
                                              float* __restrict__ WgT, float* __restrict__ WyT,
                                              float* __restrict__ WpT, float* __restrict__ LyyT,
                                              float* __restrict__ aA, float* __restrict__ sA,
                                              float* __restrict__ cbuf,
                                              float* __restrict__ smb, float* __restrict__ scb,
                                              float* __restrict__ vn) {
    int bid = blockIdx.x, tid = threadIdx.x;
    if (bid < 4096) {
        size_t i = ((size_t)bid * 256 + tid) * 8;
        float4 a = *(const float4*)(enc + i);
        float4 b = *(const float4*)(enc + i + 4);
        f16x8 o;
        o[0] = (_Float16)a.x; o[1] = (_Float16)a.y; o[2] = (_Float16)a.z; o[3] = (_Float16)a.w;
        o[4] = (_Float16)b.x; o[5] = (_Float16)b.y; o[6] = (_Float16)b.z; o[7] = (_Float16)b.w;
        *(f16x8*)(A16 + i) = o;
        return;
    }
    if (bid < 4608) {
        int x = bid - 4096;
        int kt = x & 15, nt = x >> 4;
        __shared__ _Float16 tile[32][33];
        int tx = tid & 31, ty = tid >> 5;
        int n0 = nt * 32, k0 = kt * 32;
        for (int r = 0; r < 32; r += 8) {
            int k = k0 + ty + r, n = n0 + tx;
            float v = (n < 512) ? W1[(size_t)k * 512 + n] : W2[(size_t)k * 512 + (n - 512)];
            tile[tx][ty + r] = (_Float16)v;
        }
        __syncthreads();
        for (int r = 0; r < 32; r += 8) {
            int n = n0 + ty + r, k = k0 + tx;
            WcT[(size_t)n * 512 + k] = tile[ty + r][tx];
        }
        return;
    }
    if (bid < 6080) {
        int b2 = bid - 4608;
        const float* src; float* dst; int R, C, dstride, coloff, ctiles;
        if (b2 < 256)       { src = Lss; dst = WgT;  R = 256; C = 1024; dstride = KV; coloff = 0;  ctiles = 32; }
        else if (b2 < 768)  { src = Lgs; dst = WgT;  R = 512; C = 1024; dstride = KV; coloff = HN; ctiles = 32; b2 -= 256; }
        else if (b2 < 832)  { src = Lsy; dst = WyT;  R = 256; C = 256;  dstride = KV; coloff = 0;  ctiles = 8;  b2 -= 768; }
        else if (b2 < 960)  { src = Lgy; dst = WyT;  R = 512; C = 256;  dstride = KV; coloff = HN; ctiles = 8;  b2 -= 832; }
        else if (b2 < 1088) { src = Wsm; dst = WpT;  R = 256; C = 512;  dstride = HN; coloff = 0;  ctiles = 16; b2 -= 960; }
        else if (b2 < 1216) { src = Wsc; dst = WpT + (size_t)DN * HN; R = 256; C = 512; dstride = HN; coloff = 0; ctiles = 16; b2 -= 1088; }
        else                { src = Lyy; dst = LyyT; R = 256; C = 1000; dstride = HN; coloff = 0;  ctiles = 32; b2 -= 1216; }
        int ct = b2 % ctiles, rt = b2 / ctiles;
        __shared__ float ftile[32][33];
        int c0 = ct * 32, r0 = rt * 32;
        int tx = tid & 31, ty = tid >> 5;
        for (int rr = 0; rr < 32; rr += 8) {
            int r = r0 + ty + rr, cc = c0 + tx;
            ftile[ty + rr][tx] = (r < R && cc < C) ? src[(size_t)r * C + cc] : 0.f;
        }
        __syncthreads();
        for (int rr = 0; rr < 32; rr += 8) {
            int cc = c0 + ty + rr, r = r0 + tx;
            if (cc < C && r < R) dst[(size_t)cc * dstride + coloff + r] = ftile[tx][ty + rr];
        }
        return;
    }
    if (bid < 6240) {
        int i = (bid - 6080) * 256 + tid;
        if (i < 16384) {
            aA[i] = ((i & (SS - 1)) == 0) ? 1.f : 0.f;
        } else if (i < 20480) {
            sA[i - 16384] = 0.f;
        } else if (i < 24576) {
            cbuf[i - 20480] = 0.f;
        } else if (i < 32768) {
            int j = i - 24576;
            smb[j] = Wsmb[j & (DN - 1)];
        } else {
            int j = i - 32768;
            scb[j] = Wscb[j & (DN - 1)];
        }
        return;
    }
    // vnorm
    __shared__ float red[256];
    float x0 = vM[tid], x1 = vM[tid + 256];
    red[tid] = x0 * x0 + x1 * x1;
    __syncthreads();
    for (int off = 128; off > 0; off >>= 1) {
        if (tid < off) red[tid] += red[tid + off];
        __syncthreads();
    }
    if (tid == 0) vn[0] = g[0] / sqrtf(red[0]);
}

// ---------------- f16 MFMA GEMM ----------------
__global__ __launch_bounds__(256) void gemm16_k(const _Float16* __restrict__ A16,
                                                const _Float16* __restrict__ WcT,
                                                _Float16* __restrict__ encMC) {
    __shared__ _Float16 Alds[128 * 32];
    __shared__ _Float16 Blds[128 * 32];
    int bm = blockIdx.x;
    int bn = blockIdx.y;
    int tid = threadIdx.x;
    int lane = tid & 63;
    int w = tid >> 6;
    int wr = w >> 1, wc = w & 1;
    int lr = lane & 15;
    int kg = lane >> 4;
    f32x4 acc[4][4];
#pragma unroll
    for (int i = 0; i < 4; i++)
#pragma unroll
        for (int j = 0; j < 4; j++) acc[i][j] = (f32x4){0.f, 0.f, 0.f, 0.f};
    int wavebase = tid & ~63;
    for (int k0 = 0; k0 < 512; k0 += 32) {
        __syncthreads();
#pragma unroll
        for (int is = 0; is < 2; is++) {
            int l = is * 256 + tid;
            int row = l >> 2, kgs = l & 3;
            int kp = kgs ^ ((row ^ (row >> 2)) & 3);
            gload_lds16(A16 + (size_t)(bm * 128 + row) * 512 + k0 + kp * 8,
                        (char*)Alds + (size_t)(is * 256 + wavebase) * 16);
            gload_lds16(WcT + (size_t)(bn * 128 + row) * 512 + k0 + kp * 8,
                        (char*)Blds + (size_t)(is * 256 + wavebase) * 16);
        }
        __syncthreads();
        f16x8 af[4], bf[4];
#pragma unroll
        for (int mi = 0; mi < 4; mi++) {
            int r = wr * 64 + mi * 16 + lr;
            int kp = kg ^ ((r ^ (r >> 2)) & 3);
            af[mi] = *(const f16x8*)(Alds + r * 32 + kp * 8);
        }
#pragma unroll
        for (int ni = 0; ni < 4; ni++) {
            int cgl = wc * 64 + ni * 16 + lr;
            int kp = kg ^ ((cgl ^ (cgl >> 2)) & 3);
            bf[ni] = *(const f16x8*)(Blds + cgl * 32 + kp * 8);
        }
#pragma unroll
        for (int mi = 0; mi < 4; mi++)
#pragma unroll
            for (int ni = 0; ni < 4; ni++)
                acc[mi][ni] = __builtin_amdgcn_mfma_f32_16x16x32_f16(af[mi], bf[ni], acc[mi][ni], 0, 0, 0);
    }
    int cr = lane >> 4;
#pragma unroll
    for (int mi = 0; mi < 4; mi++)
#pragma unroll
        for (int ni = 0; ni < 4; ni++) {
            int col = bn * 128 + wc * 64 + ni * 16 + lr;
#pragma unroll
            for (int j = 0; j < 4; j++) {
                int row = bm * 128 + wr * 64 + mi * 16 + cr * 4 + j;
                encMC[(size_t)row * 1024 + col] = (_Float16)acc[mi][ni][j];
            }
        }
}

// ---------------- out projection device fn ----------------
__device__ __forceinline__ void out_proj(int bid2, int tid, float* shbuf,
                                         const float* __restrict__ yv,
                                         const float* __restrict__ LyyT, const float* __restrict__ Lyyb,
                                         float* __restrict__ out, int tt) {
    for (int i = tid * 4; i < BB * HN; i += 1024)
        *(float4*)&shbuf[i] = *(const float4*)&yv[i];
    __syncthreads();
    int wave = tid >> 6, lane = tid & 63;
    int c0 = (bid2 * 4 + wave) * 4;
    for (int q = 0; q < 4; q++) {
        int cc = c0 + q;
        if (cc >= CCLS) break;
        const float* wp = LyyT + (size_t)cc * HN;
        float acc[BB] = {0.f};
#pragma unroll
        for (int k = 0; k < 4; k++) {
            int e = lane + k * 64;
            float wv = wp[e];
#pragma unroll
            for (int b = 0; b < BB; b++) acc[b] = fmaf(wv, shbuf[b * HN + e], acc[b]);
        }
#pragma unroll
        for (int b = 0; b < BB; b++)
#pragma unroll
            for (int off = 32; off > 0; off >>= 1) acc[b] += __shfl_xor(acc[b], off);
        if (lane == 0) {
            float bias = Lyyb[cc];
#pragma unroll
            for (int b = 0; b < BB; b++) out[((size_t)b * NSTEPS + tt) * CCLS + cc] = acc[b] + bias;
        }
    }
}

// ---------------- energies (blocks 0..4095, one row/wave, mask early-exit) + out(t-1) (4096..4158) ----------------
__global__ __launch_bounds__(256) void energy_out_k(const _Float16* __restrict__ encMC,
                                                    const float* __restrict__ sm, const float* __restrict__ sc,
                                                    const float* __restrict__ vM, const float* __restrict__ vC,
                                                    const float* __restrict__ vnorm, const float* __restrict__ rmono,
                                                    const int* __restrict__ len, const float* __restrict__ noise_t,
                                                    float* __restrict__ p, float* __restrict__ ech,
                                                    const float* __restrict__ yv,
                                                    const float* __restrict__ LyyT, const float* __restrict__ Lyyb,
                                                    float* __restrict__ out, int t) {
    __shared__ float shbuf[BB * HN];
    int tid = threadIdx.x;
    if (blockIdx.x >= 4096) {
        if (t > 0) out_proj(blockIdx.x - 4096, tid, shbuf, yv, LyyT, Lyyb, out, t - 1);
        return;
    }
    int wave = blockIdx.x * 4 + (tid >> 6);
    int lane = tid & 63;
    int b = wave >> 10;
    int si = wave & 1023;
    // mask early-exit: skip all loads/compute for masked rows (no barrier in this path)
    if (si >= len[b]) {
        if (lane == 0) {
            p[b * SS + si] = 0.f;
            ech[b * SS + si] = -INFINITY;
        }
        return;
    }
    const f16x8* row = (const f16x8*)(encMC + (size_t)wave * 1024);
    f16x8 em = row[lane];
    f16x8 ec = row[64 + lane];
    int d0 = lane * 8;
    float4 sma = *(const float4*)&sm[b * DN + d0];
    float4 smbv = *(const float4*)&sm[b * DN + d0 + 4];
    float4 sca = *(const float4*)&sc[b * DN + d0];
    float4 scbv = *(const float4*)&sc[b * DN + d0 + 4];
    float4 vma = *(const float4*)&vM[d0];
    float4 vmb = *(const float4*)&vM[d0 + 4];
    float4 vca = *(const float4*)&vC[d0];
    float4 vcb = *(const float4*)&vC[d0 + 4];
    float smv[8] = {sma.x, sma.y, sma.z, sma.w, smbv.x, smbv.y, smbv.z, smbv.w};
    float scv[8] = {sca.x, sca.y, sca.z, sca.w, scbv.x, scbv.y, scbv.z, scbv.w};
    float vmv[8] = {vma.x, vma.y, vma.z, vma.w, vmb.x, vmb.y, vmb.z, vmb.w};
    float vcv[8] = {vca.x, vca.y, vca.z, vca.w, vcb.x, vcb.y, vcb.z, vcb.w};
    float s1 = 0.f, s2 = 0.f;
#pragma unroll
    for (int j = 0; j < 8; j++) {
        s1 += ftanh((float)em[j] + smv[j]) * vmv[j];
        s2 += ftanh((float)ec[j] + scv[j]) * vcv[j];
    }
#pragma unroll
    for (int off = 32; off > 0; off >>= 1) {
        s1 += __shfl_xor(s1, off);
        s2 += __shfl_xor(s2, off);
    }
    if (lane == 0) {
        p[b * SS + si] = fsigm(vnorm[0] * s1 + rmono[0] + noise_t[b * SS + si]);
        ech[b * SS + si] = s2;
    }
}

// ---------------- fused scan (wave 0) + coalesced ctx partials: grid (16,8) x 512 thr ----------------
__global__ __launch_bounds__(512) void scanctx_k(const float* __restrict__ p,
                                                 const float* __restrict__ aprev,
                                                 const float* __restrict__ ech,
                                                 const _Float16* __restrict__ enc16,
                                                 float* __restrict__ anew,
                                                 float* __restrict__ part8) {
    __shared__ float betaL[SS];
    __shared__ float red[8][DN];
    int b = blockIdx.x, ch = blockIdx.y;
    int tid = threadIdx.x;
    if (tid < 64) {
        int l = tid;
        int base = b * SS + l * 16;
        float pv[16], ap[16], eh[16];
#pragma unroll
        for (int k = 0; k < 16; k += 4) {
            *(float4*)&pv[k] = *(const float4*)&p[base + k];
            *(float4*)&ap[k] = *(const float4*)&aprev[base + k];
            *(float4*)&eh[k] = *(const float4*)&ech[base + k];
        }
        float ls[16];
        float run = 0.f;
#pragma unroll
        for (int k = 0; k < 16; k++) {
            float lf = __logf(fminf(fmaxf(1.f - pv[k], 1e-8f), 1.f));
            if (l == 63 && k == 15) lf = 0.f;
            run += lf;
            ls[k] = run;
        }
        float incl = run;
#pragma unroll
        for (int off = 1; off < 64; off <<= 1) {
            float n = __shfl_up(incl, off);
            if (l >= off) incl += n;
        }
        float basew = incl - run;
        float cpp[16];
#pragma unroll
        for (int k = 0; k < 16; k++)
            cpp[k] = __expf(basew + (k ? ls[k - 1] : 0.f));
        float us[16];
        float run2 = 0.f;
#pragma unroll
        for (int k = 0; k < 16; k++) {
            run2 += ap[k] / fminf(fmaxf(cpp[k], 1e-8f), 1.f);
            us[k] = run2;
        }
        float incl2 = run2;
#pragma unroll
        for (int off = 1; off < 64; off <<= 1) {
            float n = __shfl_up(incl2, off);
            if (l >= off) incl2 += n;
        }
        float basew2 = incl2 - run2;
        float al[16];
#pragma unroll
        for (int k = 0; k < 16; k++)
            al[k] = fminf(fmaxf(pv[k] * (cpp[k] * (basew2 + us[k])), 1e-8f), 1.f);
        if (ch == 0) {
#pragma unroll
            for (int k = 0; k < 16; k += 4)
                *(float4*)&anew[base + k] = *(float4*)&al[k];
        }
        float mx = eh[0];
#pragma unroll
        for (int k = 1; k < 16; k++) mx = fmaxf(mx, eh[k]);
#pragma unroll
        for (int off = 32; off > 0; off >>= 1) mx = fmaxf(mx, __shfl_xor(mx, off));
        float ex[16];
#pragma unroll
        for (int k = 0; k < 16; k++) ex[k] = fmaxf(__expf(eh[k] - mx), 1e-5f);
        float exm1 = __shfl_up(ex[15], 1); if (l == 0) exm1 = 0.f;
        float exm2 = __shfl_up(ex[14], 1); if (l == 0) exm2 = 0.f;
        float exm3 = __shfl_up(ex[13], 1); if (l == 0) exm3 = 0.f;
        float r[16];
        {
            float dd0 = ex[0] + exm1 + exm2 + exm3;
            float dd1 = ex[1] + ex[0] + exm1 + exm2;
            float dd2 = ex[2] + ex[1] + ex[0] + exm1;
            r[0] = al[0] / fmaxf(dd0, 1e-10f);
            r[1] = al[1] / fmaxf(dd1, 1e-10f);
            r[2] = al[2] / fmaxf(dd2, 1e-10f);
        }
#pragma unroll
        for (int k = 3; k < 16; k++)
            r[k] = al[k] / fmaxf(ex[k] + ex[k - 1] + ex[k - 2] + ex[k - 3], 1e-10f);
        float rp1 = __shfl_down(r[0], 1); if (l == 63) rp1 = 0.f;
        float rp2 = __shfl_down(r[1], 1); if (l == 63) rp2 = 0.f;
        float rp3 = __shfl_down(r[2], 1); if (l == 63) rp3 = 0.f;
        float bt[16];
#pragma unroll
        for (int k = 0; k < 13; k++)
            bt[k] = ex[k] * (r[k] + r[k + 1] + r[k + 2] + r[k + 3]);
        bt[13] = ex[13] * (r[13] + r[14] + r[15] + rp1);
        bt[14] = ex[14] * (r[14] + r[15] + rp1 + rp2);
        bt[15] = ex[15] * (r[15] + rp1 + rp2 + rp3);
#pragma unroll
        for (int k = 0; k < 16; k++) betaL[l * 16 + k] = bt[k];
    }
    __syncthreads();
    // ---- ctx partial over chunk ch (rows s0..s0+127), coalesced f16x8 ----
    int wv = tid >> 6, lane = tid & 63;
    int s0 = ch * 128;
    float acc[8] = {0.f};
    const _Float16* ebase = enc16 + ((size_t)(b * SS + s0)) * DN + lane * 8;
    const float* bp = betaL + s0;
#pragma unroll 4
    for (int rr = 0; rr < 16; rr++) {
        int s = wv + rr * 8;
        float bv = bp[s];
        f16x8 ld = *(const f16x8*)(ebase + (size_t)s * DN);
#pragma unroll
        for (int j = 0; j < 8; j++) acc[j] = fmaf(bv, (float)ld[j], acc[j]);
    }
#pragma unroll
    for (int j = 0; j < 8; j++) red[wv][lane * 8 + j] = acc[j];
    __syncthreads();
    float s = 0.f;
#pragma unroll
    for (int wq = 0; wq < 8; wq++) s += red[wq][tid];
    part8[((size_t)(b * 8 + ch)) * DN + tid] = s;
}

// ---------------- fused gates + LSTM: 64 blocks x 512 thr ----------------
__global__ __launch_bounds__(512) void gl_k(const float* __restrict__ part8,
                                            const float* __restrict__ sIn,
                                            const float* __restrict__ WgT,
                                            const int* __restrict__ target, int t,
                                            const float* __restrict__ Lys, const float* __restrict__ Lgsb,
                                            float* __restrict__ c, float* __restrict__ sOut,
                                            float* __restrict__ ctxbuf) {
    __shared__ float xl[BB * KV];
    __shared__ float recL[16][BB];
    int tid = threadIdx.x;
    for (int i = tid; i < BB * HN; i += 512)
        xl[(i >> 8) * KV + (i & (HN - 1))] = sIn[i];
    for (int i = tid; i < BB * DN; i += 512) {
        int bb = i >> 9, d = i & (DN - 1);
        const float* pp = part8 + (size_t)bb * (8 * DN) + d;
        float v = ((pp[0] + pp[DN]) + (pp[2 * DN] + pp[3 * DN])) +
                  ((pp[4 * DN] + pp[5 * DN]) + (pp[6 * DN] + pp[7 * DN]));
        xl[bb * KV + HN + d] = v;
        if (blockIdx.x == 0) ctxbuf[i] = v;
    }
    __syncthreads();
    int wv = tid >> 6, lane = tid & 63;
    int h0 = blockIdx.x * 4;
    int ri0 = wv * 2, ri1 = ri0 + 1;
    const float* w0p = WgT + (size_t)((ri0 >> 2) * HN + h0 + (ri0 & 3)) * KV;
    const float* w1p = WgT + (size_t)((ri1 >> 2) * HN + h0 + (ri1 & 3)) * KV;
    float acc0[BB] = {0.f}, acc1[BB] = {0.f};
#pragma unroll
    for (int j = 0; j < 12; j++) {
        int e = lane + j * 64;
        float w0 = w0p[e], w1 = w1p[e];
#pragma unroll
        for (int b = 0; b < BB; b++) {
            float xv = xl[b * KV + e];
            acc0[b] = fmaf(w0, xv, acc0[b]);
            acc1[b] = fmaf(w1, xv, acc1[b]);
        }
    }
#pragma unroll
    for (int b = 0; b < BB; b++)
#pragma unroll
        for (int off = 32; off > 0; off >>= 1) {
            acc0[b] += __shfl_xor(acc0[b], off);
            acc1[b] += __shfl_xor(acc1[b], off);
        }
    if (lane == 0) {
#pragma unroll
        for (int b = 0; b < BB; b++) {
            recL[ri0][b] = acc0[b];
            recL[ri1][b] = acc1[b];
        }
    }
    __syncthreads();
    if (tid < 64) {
        int b = tid & 15, hh = tid >> 4;
        int h = h0 + hh;
        int tgt = target[b * NSTEPS + t];
        const float* ys = Lys + (size_t)tgt * G4;
        float ri = recL[0 * 4 + hh][b] + ys[h] + Lgsb[h];
        float rf = recL[1 * 4 + hh][b] + ys[h + HN] + Lgsb[h + HN];
        float rg = recL[2 * 4 + hh][b] + ys[h + 2 * HN] + Lgsb[h + 2 * HN];
        float ro = recL[3 * 4 + hh][b] + ys[h + 3 * HN] + Lgsb[h + 3 * HN];
        float cn = fsigm(rf) * c[b * HN + h] + fsigm(ri) * ftanh(rg);
        float sn = fsigm(ro) * ftanh(cn);
        c[b * HN + h] = cn;
        sOut[b * HN + h] = sn;
    }
}

// ---------------- y gate (0..15) + next-step proj (16..79) ----------------
__global__ __launch_bounds__(256) void ypj_k(const float* __restrict__ sNew,
                                             const float* __restrict__ ctxbuf,
                                             const float* __restrict__ WyT, const float* __restrict__ Lgyb,
                                             const float* __restrict__ WpT,
                                             const float* __restrict__ Wsmb, const float* __restrict__ Wscb,
                                             float* __restrict__ yv,
                                             float* __restrict__ smb, float* __restrict__ scb) {
    __shared__ float sl[BB * KV];
    int tid = threadIdx.x;
    for (int i = tid; i < BB * HN; i += 256)
        sl[(i >> 8) * KV + (i & (HN - 1))] = sNew[i];
    for (int i = tid; i < BB * DN; i += 256)
        sl[(i >> 9) * KV + HN + (i & (DN - 1))] = ctxbuf[i];
    __syncthreads();
    int wave = tid >> 6, lane = tid & 63;
    if (blockIdx.x < 16) {
        int h0 = blockIdx.x * 16 + wave * 4;
        for (int q = 0; q < 4; q++) {
            int h = h0 + q;
            const float* wp = WyT + (size_t)h * KV;
            float acc[BB] = {0.f};
#pragma unroll
            for (int j = 0; j < 12; j++) {
                int e = lane + j * 64;
                float wv = wp[e];
#pragma unroll
                for (int b = 0; b < BB; b++) acc[b] = fmaf(wv, sl[b * KV + e], acc[b]);
            }
#pragma unroll
            for (int b = 0; b < BB; b++)
#pragma unroll
                for (int off = 32; off > 0; off >>= 1) acc[b] += __shfl_xor(acc[b], off);
            if (lane == 0) {
#pragma unroll
                for (int b = 0; b < BB; b++) yv[b * HN + h] = ftanh(acc[b] + Lgyb[h]);
            }
        }
    } else {
        int j0 = (blockIdx.x - 16) * 16 + wave * 4;
        for (int q = 0; q < 4; q++) {
            int jc = j0 + q;
            const float* wp = WpT + (size_t)jc * HN;
            float acc[BB] = {0.f};
#pragma unroll
            for (int k = 0; k < 4; k++) {
                int e = lane + k * 64;
                float wv = wp[e];
#pragma unroll
                for (int b = 0; b < BB; b++) acc[b] = fmaf(wv, sl[b * KV + e], acc[b]);
            }
#pragma unroll
            for (int b = 0; b < BB; b++)
#pragma unroll
                for (int off = 32; off > 0; off >>= 1) acc[b] += __shfl_xor(acc[b], off);
            if (lane == 0) {
                if (jc < DN) {
#pragma unroll
                    for (int b = 0; b < BB; b++) smb[b * DN + jc] = acc[b] + Wsmb[jc];
                } else {
                    int jj = jc - DN;
#pragma unroll
                    for (int b = 0; b < BB; b++) scb[b * DN + jj] = acc[b] + Wscb[jj];
                }
            }
        }
    }
}

// ---------------- standalone out projection (final step) ----------------
__global__ __launch_bounds__(256) void out_k(const float* __restrict__ yv,
                                             const float* __restrict__ LyyT, const float* __restrict__ Lyyb,
                                             float* __restrict__ out, int t) {
    __shared__ float shbuf[BB * HN];
    out_proj(blockIdx.x, threadIdx.x, shbuf, yv, LyyT, Lyyb, out, t);
}

extern "C" void kernel_launch(void* const* d_in, const int* in_sizes, int n_in,
                              void* d_out, int out_size, void* d_ws, size_t ws_size,
                              hipStream_t stream) {
    const float* enc  = (const float*)d_in[0];
    const int*   target = (const int*)d_in[1];
    const int*   len  = (const int*)d_in[2];
    const float* noise = (const float*)d_in[3];
    const float* Wsm  = (const float*)d_in[4];
    const float* Wsmb = (const float*)d_in[5];
    const float* WhM  = (const float*)d_in[6];
    const float* vM   = (const float*)d_in[7];
    const float* g    = (const float*)d_in[8];
    const float* rm   = (const float*)d_in[9];
    const float* Wsc  = (const float*)d_in[10];
    const float* Wscb = (const float*)d_in[11];
    const float* WhC  = (const float*)d_in[12];
    const float* vC   = (const float*)d_in[13];
    const float* Lsy  = (const float*)d_in[14];
    const float* Lgy  = (const float*)d_in[15];
    const float* Lgyb = (const float*)d_in[16];
    const float* Lyy  = (const float*)d_in[17];
    const float* Lyyb = (const float*)d_in[18];
    const float* Lys  = (const float*)d_in[19];
    const float* Lss  = (const float*)d_in[20];
    const float* Lgs  = (const float*)d_in[21];
    const float* Lgsb = (const float*)d_in[22];
    float* out = (float*)d_out;

    char* w = (char*)d_ws;
    size_t off = 0;
    auto alloc = [&](size_t bytes) { void* pp = w + off; off += (bytes + 255) & ~(size_t)255; return pp; };
    _Float16* A16   = (_Float16*)alloc((size_t)BB * SS * DN * 2);
    _Float16* WcT   = (_Float16*)alloc((size_t)1024 * 512 * 2);
    _Float16* encMC = (_Float16*)alloc((size_t)BB * SS * 1024 * 2);
    float* WgT  = (float*)alloc((size_t)G4 * KV * 4);
    float* WyT  = (float*)alloc((size_t)HN * KV * 4);
    float* WpT  = (float*)alloc((size_t)G4 * HN * 4);
    float* LyyT = (float*)alloc((size_t)CCLS * HN * 4);
    float* smb   = (float*)alloc(BB * DN * 4);
    float* scb   = (float*)alloc(BB * DN * 4);
    float* pbuf  = (float*)alloc(BB * SS * 4);
    float* ech   = (float*)alloc(BB * SS * 4);
    float* aA    = (float*)alloc(BB * SS * 4);
    float* aBf   = (float*)alloc(BB * SS * 4);
    float* part8 = (float*)alloc((size_t)BB * 8 * DN * 4);
    float* ctxbuf = (float*)alloc((size_t)BB * DN * 4);
    float* sA    = (float*)alloc((size_t)BB * HN * 4);
    float* sB    = (float*)alloc((size_t)BB * HN * 4);
    float* yvb   = (float*)alloc((size_t)BB * HN * 4);
    float* cbuf  = (float*)alloc(BB * HN * 4);
    float* vn    = (float*)alloc(16);
    (void)ws_size; (void)in_sizes; (void)n_in; (void)out_size;

    // ---- preamble (2 launches) ----
    prep_k<<<6241, 256, 0, stream>>>(enc, WhM, WhC, Lss, Lgs, Lsy, Lgy, Wsm, Wsc, Lyy,
                                     vM, g, Wsmb, Wscb,
                                     A16, WcT, WgT, WyT, WpT, LyyT,
                                     aA, sA, cbuf, smb, scb, vn);
    gemm16_k<<<dim3(128, 8), 256, 0, stream>>>(A16, WcT, encMC);

    for (int t = 0; t < NSTEPS; t++) {
        float* ain  = (t % 2 == 0) ? aA : aBf;
        float* aout = (t % 2 == 0) ? aBf : aA;
        float* sIn  = (t % 2 == 0) ? sA : sB;
        float* sOut = (t % 2 == 0) ? sB : sA;
        energy_out_k<<<4159, 256, 0, stream>>>(encMC, smb, scb, vM, vC, vn, rm,
                                               len, noise + (size_t)t * BB * SS, pbuf, ech,
                                               yvb, LyyT, Lyyb, out, t);
        scanctx_k<<<dim3(BB, 8), 512, 0, stream>>>(pbuf, ain, ech, A16, aout, part8);
        gl_k<<<64, 512, 0, stream>>>(part8, sIn, WgT, target, t, Lys, Lgsb, cbuf, sOut, ctxbuf);
        ypj_k<<<80, 256, 0, stream>>>(sOut, ctxbuf, WyT, Lgyb, WpT, Wsmb, Wscb, yvb, smb, scb);
    }
    out_k<<<63, 256, 0, stream>>>(yvb, LyyT, Lyyb, out, NSTEPS - 1);
}

// Round 12
// 455.432 us; speedup vs baseline: 1.0923x; 1.0923x over previous
//
#include <hip/hip_runtime.h>
#include <math.h>
#include <float.h>

#define HN 256
#define DN 512
#define CCLS 1000
#define BB 16
#define SS 1024
#define NSTEPS 8
#define G4 1024   // 4*H
#define KV 768    // s(256) + ctx(512)

using f16x8 = __attribute__((ext_vector_type(8))) _Float16;
using f32x4 = __attribute__((ext_vector_type(4))) float;

__device__ __forceinline__ void gload_lds16(const void* g, void* l) {
    __builtin_amdgcn_global_load_lds((const __attribute__((address_space(1))) void*)g,
                                     (__attribute__((address_space(3))) void*)l, 16, 0, 0);
}

// fast reciprocal: v_rcp_f32 (~1 ulp; fine vs 1.4e-2 threshold)
__device__ __forceinline__ float frcp(float x) {
    return __builtin_amdgcn_rcpf(x);
}
// NaN-safe fast tanh: 1 - 2/(e^{2x}+1); e=inf -> 1, e=0 -> -1
__device__ __forceinline__ float ftanh(float x) {
    float e = __expf(2.f * x);
    return 1.f - 2.f * frcp(e + 1.f);
}
__device__ __forceinline__ float fsigm(float x) {
    return frcp(1.f + __expf(-x));
}

// ================= prep: conv_enc (0..4095) | convW (4096..4607) | transAll (4608..6079)
//                   | init (6080..6239) | vnorm (6240) =================
__global__ __launch_bounds__(256) void prep_k(const float* __restrict__ enc,
                                              const float* __restrict__ W1, const float* __restrict__ W2,
                                              const float* __restrict__ Lss, const float* __restrict__ Lgs,
                                              const float* __restrict__ Lsy, const float* __restrict__ Lgy,
                                              const float* __restrict__ Wsm, const float* __restrict__ Wsc,
                                              const float* __restrict__ Lyy,
                                              const float* __restrict__ vM, const float* __restrict__ g,
                                              const float* __restrict__ Wsmb, const float* __restrict__ Wscb,
                                              _Float16* __restrict__ A16, _Float16* __restrict__ WcT,
                                              float* __restrict__ WgT, float* __restrict__ WyT,
                                              float* __restrict__ WpT, float* __restrict__ LyyT,
                                              float* __restrict__ aA, float* __restrict__ sA,
                                              float* __restrict__ cbuf,
                                              float* __restrict__ smb, float* __restrict__ scb,
                                              float* __restrict__ vn) {
    int bid = blockIdx.x, tid = threadIdx.x;
    if (bid < 4096) {
        size_t i = ((size_t)bid * 256 + tid) * 8;
        float4 a = *(const float4*)(enc + i);
        float4 b = *(const float4*)(enc + i + 4);
        f16x8 o;
        o[0] = (_Float16)a.x; o[1] = (_Float16)a.y; o[2] = (_Float16)a.z; o[3] = (_Float16)a.w;
        o[4] = (_Float16)b.x; o[5] = (_Float16)b.y; o[6] = (_Float16)b.z; o[7] = (_Float16)b.w;
        *(f16x8*)(A16 + i) = o;
        return;
    }
    if (bid < 4608) {
        int x = bid - 4096;
        int kt = x & 15, nt = x >> 4;
        __shared__ _Float16 tile[32][33];
        int tx = tid & 31, ty = tid >> 5;
        int n0 = nt * 32, k0 = kt * 32;
        for (int r = 0; r < 32; r += 8) {
            int k = k0 + ty + r, n = n0 + tx;
            float v = (n < 512) ? W1[(size_t)k * 512 + n] : W2[(size_t)k * 512 + (n - 512)];
            tile[tx][ty + r] = (_Float16)v;
        }
        __syncthreads();
        for (int r = 0; r < 32; r += 8) {
            int n = n0 + ty + r, k = k0 + tx;
            WcT[(size_t)n * 512 + k] = tile[ty + r][tx];
        }
        return;
    }
    if (bid < 6080) {
        int b2 = bid - 4608;
        const float* src; float* dst; int R, C, dstride, coloff, ctiles;
        if (b2 < 256)       { src = Lss; dst = WgT;  R = 256; C = 1024; dstride = KV; coloff = 0;  ctiles = 32; }
        else if (b2 < 768)  { src = Lgs; dst = WgT;  R = 512; C = 1024; dstride = KV; coloff = HN; ctiles = 32; b2 -= 256; }
        else if (b2 < 832)  { src = Lsy; dst = WyT;  R = 256; C = 256;  dstride = KV; coloff = 0;  ctiles = 8;  b2 -= 768; }
        else if (b2 < 960)  { src = Lgy; dst = WyT;  R = 512; C = 256;  dstride = KV; coloff = HN; ctiles = 8;  b2 -= 832; }
        else if (b2 < 1088) { src = Wsm; dst = WpT;  R = 256; C = 512;  dstride = HN; coloff = 0;  ctiles = 16; b2 -= 960; }
        else if (b2 < 1216) { src = Wsc; dst = WpT + (size_t)DN * HN; R = 256; C = 512; dstride = HN; coloff = 0; ctiles = 16; b2 -= 1088; }
        else                { src = Lyy; dst = LyyT; R = 256; C = 1000; dstride = HN; coloff = 0;  ctiles = 32; b2 -= 1216; }
        int ct = b2 % ctiles, rt = b2 / ctiles;
        __shared__ float ftile[32][33];
        int c0 = ct * 32, r0 = rt * 32;
        int tx = tid & 31, ty = tid >> 5;
        for (int rr = 0; rr < 32; rr += 8) {
            int r = r0 + ty + rr, cc = c0 + tx;
            ftile[ty + rr][tx] = (r < R && cc < C) ? src[(size_t)r * C + cc] : 0.f;
        }
        __syncthreads();
        for (int rr = 0; rr < 32; rr += 8) {
            int cc = c0 + ty + rr, r = r0 + tx;
            if (cc < C && r < R) dst[(size_t)cc * dstride + coloff + r] = ftile[tx][ty + rr];
        }
        return;
    }
    if (bid < 6240) {
        int i = (bid - 6080) * 256 + tid;
        if (i < 16384) {
            aA[i] = ((i & (SS - 1)) == 0) ? 1.f : 0.f;
        } else if (i < 20480) {
            sA[i - 16384] = 0.f;
        } else if (i < 24576) {
            cbuf[i - 20480] = 0.f;
        } else if (i < 32768) {
            int j = i - 24576;
            smb[j] = Wsmb[j & (DN - 1)];
        } else {
            int j = i - 32768;
            scb[j] = Wscb[j & (DN - 1)];
        }
        return;
    }
    // vnorm
    __shared__ float red[256];
    float x0 = vM[tid], x1 = vM[tid + 256];
    red[tid] = x0 * x0 + x1 * x1;
    __syncthreads();
    for (int off = 128; off > 0; off >>= 1) {
        if (tid < off) red[tid] += red[tid + off];
        __syncthreads();
    }
    if (tid == 0) vn[0] = g[0] / sqrtf(red[0]);
}

// ---------------- f16 MFMA GEMM ----------------
__global__ __launch_bounds__(256) void gemm16_k(const _Float16* __restrict__ A16,
                                                const _Float16* __restrict__ WcT,
                                                _Float16* __restrict__ encMC) {
    __shared__ _Float16 Alds[128 * 32];
    __shared__ _Float16 Blds[128 * 32];
    int bm = blockIdx.x;
    int bn = blockIdx.y;
    int tid = threadIdx.x;
    int lane = tid & 63;
    int w = tid >> 6;
    int wr = w >> 1, wc = w & 1;
    int lr = lane & 15;
    int kg = lane >> 4;
    f32x4 acc[4][4];
#pragma unroll
    for (int i = 0; i < 4; i++)
#pragma unroll
        for (int j = 0; j < 4; j++) acc[i][j] = (f32x4){0.f, 0.f, 0.f, 0.f};
    int wavebase = tid & ~63;
    for (int k0 = 0; k0 < 512; k0 += 32) {
        __syncthreads();
#pragma unroll
        for (int is = 0; is < 2; is++) {
            int l = is * 256 + tid;
            int row = l >> 2, kgs = l & 3;
            int kp = kgs ^ ((row ^ (row >> 2)) & 3);
            gload_lds16(A16 + (size_t)(bm * 128 + row) * 512 + k0 + kp * 8,
                        (char*)Alds + (size_t)(is * 256 + wavebase) * 16);
            gload_lds16(WcT + (size_t)(bn * 128 + row) * 512 + k0 + kp * 8,
                        (char*)Blds + (size_t)(is * 256 + wavebase) * 16);
        }
        __syncthreads();
        f16x8 af[4], bf[4];
#pragma unroll
        for (int mi = 0; mi < 4; mi++) {
            int r = wr * 64 + mi * 16 + lr;
            int kp = kg ^ ((r ^ (r >> 2)) & 3);
            af[mi] = *(const f16x8*)(Alds + r * 32 + kp * 8);
        }
#pragma unroll
        for (int ni = 0; ni < 4; ni++) {
            int cgl = wc * 64 + ni * 16 + lr;
            int kp = kg ^ ((cgl ^ (cgl >> 2)) & 3);
            bf[ni] = *(const f16x8*)(Blds + cgl * 32 + kp * 8);
        }
#pragma unroll
        for (int mi = 0; mi < 4; mi++)
#pragma unroll
            for (int ni = 0; ni < 4; ni++)
                acc[mi][ni] = __builtin_amdgcn_mfma_f32_16x16x32_f16(af[mi], bf[ni], acc[mi][ni], 0, 0, 0);
    }
    int cr = lane >> 4;
#pragma unroll
    for (int mi = 0; mi < 4; mi++)
#pragma unroll
        for (int ni = 0; ni < 4; ni++) {
            int col = bn * 128 + wc * 64 + ni * 16 + lr;
#pragma unroll
            for (int j = 0; j < 4; j++) {
                int row = bm * 128 + wr * 64 + mi * 16 + cr * 4 + j;
                encMC[(size_t)row * 1024 + col] = (_Float16)acc[mi][ni][j];
            }
        }
}

// ---------------- out projection device fn ----------------
__device__ __forceinline__ void out_proj(int bid2, int tid, float* shbuf,
                                         const float* __restrict__ yv,
                                         const float* __restrict__ LyyT, const float* __restrict__ Lyyb,
                                         float* __restrict__ out, int tt) {
    for (int i = tid * 4; i < BB * HN; i += 1024)
        *(float4*)&shbuf[i] = *(const float4*)&yv[i];
    __syncthreads();
    int wave = tid >> 6, lane = tid & 63;
    int c0 = (bid2 * 4 + wave) * 4;
    for (int q = 0; q < 4; q++) {
        int cc = c0 + q;
        if (cc >= CCLS) break;
        const float* wp = LyyT + (size_t)cc * HN;
        float acc[BB] = {0.f};
#pragma unroll
        for (int k = 0; k < 4; k++) {
            int e = lane + k * 64;
            float wv = wp[e];
#pragma unroll
            for (int b = 0; b < BB; b++) acc[b] = fmaf(wv, shbuf[b * HN + e], acc[b]);
        }
#pragma unroll
        for (int b = 0; b < BB; b++)
#pragma unroll
            for (int off = 32; off > 0; off >>= 1) acc[b] += __shfl_xor(acc[b], off);
        if (lane == 0) {
            float bias = Lyyb[cc];
#pragma unroll
            for (int b = 0; b < BB; b++) out[((size_t)b * NSTEPS + tt) * CCLS + cc] = acc[b] + bias;
        }
    }
}

// ---------------- energies (blocks 0..4095, one row/wave, mask early-exit) + out(t-1) (4096..4158) ----------------
__global__ __launch_bounds__(256) void energy_out_k(const _Float16* __restrict__ encMC,
                                                    const float* __restrict__ sm, const float* __restrict__ sc,
                                                    const float* __restrict__ vM, const float* __restrict__ vC,
                                                    const float* __restrict__ vnorm, const float* __restrict__ rmono,
                                                    const int* __restrict__ len, const float* __restrict__ noise_t,
                                                    float* __restrict__ p, float* __restrict__ ech,
                                                    const float* __restrict__ yv,
                                                    const float* __restrict__ LyyT, const float* __restrict__ Lyyb,
                                                    float* __restrict__ out, int t) {
    __shared__ float shbuf[BB * HN];
    int tid = threadIdx.x;
    if (blockIdx.x >= 4096) {
        if (t > 0) out_proj(blockIdx.x - 4096, tid, shbuf, yv, LyyT, Lyyb, out, t - 1);
        return;
    }
    int wave = blockIdx.x * 4 + (tid >> 6);
    int lane = tid & 63;
    int b = wave >> 10;
    int si = wave & 1023;
    // mask early-exit: skip all loads/compute for masked rows (no barrier in this path)
    if (si >= len[b]) {
        if (lane == 0) {
            p[b * SS + si] = 0.f;
            ech[b * SS + si] = -INFINITY;
        }
        return;
    }
    const f16x8* row = (const f16x8*)(encMC + (size_t)wave * 1024);
    f16x8 em = row[lane];
    f16x8 ec = row[64 + lane];
    int d0 = lane * 8;
    float4 sma = *(const float4*)&sm[b * DN + d0];
    float4 smbv = *(const float4*)&sm[b * DN + d0 + 4];
    float4 sca = *(const float4*)&sc[b * DN + d0];
    float4 scbv = *(const float4*)&sc[b * DN + d0 + 4];
    float4 vma = *(const float4*)&vM[d0];
    float4 vmb = *(const float4*)&vM[d0 + 4];
    float4 vca = *(const float4*)&vC[d0];
    float4 vcb = *(const float4*)&vC[d0 + 4];
    float smv[8] = {sma.x, sma.y, sma.z, sma.w, smbv.x, smbv.y, smbv.z, smbv.w};
    float scv[8] = {sca.x, sca.y, sca.z, sca.w, scbv.x, scbv.y, scbv.z, scbv.w};
    float vmv[8] = {vma.x, vma.y, vma.z, vma.w, vmb.x, vmb.y, vmb.z, vmb.w};
    float vcv[8] = {vca.x, vca.y, vca.z, vca.w, vcb.x, vcb.y, vcb.z, vcb.w};
    float s1 = 0.f, s2 = 0.f;
#pragma unroll
    for (int j = 0; j < 8; j++) {
        s1 += ftanh((float)em[j] + smv[j]) * vmv[j];
        s2 += ftanh((float)ec[j] + scv[j]) * vcv[j];
    }
#pragma unroll
    for (int off = 32; off > 0; off >>= 1) {
        s1 += __shfl_xor(s1, off);
        s2 += __shfl_xor(s2, off);
    }
    if (lane == 0) {
        p[b * SS + si] = fsigm(vnorm[0] * s1 + rmono[0] + noise_t[b * SS + si]);
        ech[b * SS + si] = s2;
    }
}

// ---------------- fused scan (wave 0) + coalesced ctx partials: grid (16,8) x 512 thr ----------------
__global__ __launch_bounds__(512) void scanctx_k(const float* __restrict__ p,
                                                 const float* __restrict__ aprev,
                                                 const float* __restrict__ ech,
                                                 const _Float16* __restrict__ enc16,
                                                 float* __restrict__ anew,
                                                 float* __restrict__ part8) {
    __shared__ float betaL[SS];
    __shared__ float red[8][DN];
    int b = blockIdx.x, ch = blockIdx.y;
    int tid = threadIdx.x;
    if (tid < 64) {
        int l = tid;
        int base = b * SS + l * 16;
        float pv[16], ap[16], eh[16];
#pragma unroll
        for (int k = 0; k < 16; k += 4) {
            *(float4*)&pv[k] = *(const float4*)&p[base + k];
            *(float4*)&ap[k] = *(const float4*)&aprev[base + k];
            *(float4*)&eh[k] = *(const float4*)&ech[base + k];
        }
        float ls[16];
        float run = 0.f;
#pragma unroll
        for (int k = 0; k < 16; k++) {
            float lf = __logf(fminf(fmaxf(1.f - pv[k], 1e-8f), 1.f));
            if (l == 63 && k == 15) lf = 0.f;
            run += lf;
            ls[k] = run;
        }
        float incl = run;
#pragma unroll
        for (int off = 1; off < 64; off <<= 1) {
            float n = __shfl_up(incl, off);
            if (l >= off) incl += n;
        }
        float basew = incl - run;
        float cpp[16];
#pragma unroll
        for (int k = 0; k < 16; k++)
            cpp[k] = __expf(basew + (k ? ls[k - 1] : 0.f));
        float us[16];
        float run2 = 0.f;
#pragma unroll
        for (int k = 0; k < 16; k++) {
            run2 += ap[k] * frcp(fminf(fmaxf(cpp[k], 1e-8f), 1.f));
            us[k] = run2;
        }
        float incl2 = run2;
#pragma unroll
        for (int off = 1; off < 64; off <<= 1) {
            float n = __shfl_up(incl2, off);
            if (l >= off) incl2 += n;
        }
        float basew2 = incl2 - run2;
        float al[16];
#pragma unroll
        for (int k = 0; k < 16; k++)
            al[k] = fminf(fmaxf(pv[k] * (cpp[k] * (basew2 + us[k])), 1e-8f), 1.f);
        if (ch == 0) {
#pragma unroll
            for (int k = 0; k < 16; k += 4)
                *(float4*)&anew[base + k] = *(float4*)&al[k];
        }
        float mx = eh[0];
#pragma unroll
        for (int k = 1; k < 16; k++) mx = fmaxf(mx, eh[k]);
#pragma unroll
        for (int off = 32; off > 0; off >>= 1) mx = fmaxf(mx, __shfl_xor(mx, off));
        float ex[16];
#pragma unroll
        for (int k = 0; k < 16; k++) ex[k] = fmaxf(__expf(eh[k] - mx), 1e-5f);
        float exm1 = __shfl_up(ex[15], 1); if (l == 0) exm1 = 0.f;
        float exm2 = __shfl_up(ex[14], 1); if (l == 0) exm2 = 0.f;
        float exm3 = __shfl_up(ex[13], 1); if (l == 0) exm3 = 0.f;
        float r[16];
        {
            float dd0 = ex[0] + exm1 + exm2 + exm3;
            float dd1 = ex[1] + ex[0] + exm1 + exm2;
            float dd2 = ex[2] + ex[1] + ex[0] + exm1;
            r[0] = al[0] * frcp(fmaxf(dd0, 1e-10f));
            r[1] = al[1] * frcp(fmaxf(dd1, 1e-10f));
            r[2] = al[2] * frcp(fmaxf(dd2, 1e-10f));
        }
#pragma unroll
        for (int k = 3; k < 16; k++)
            r[k] = al[k] * frcp(fmaxf(ex[k] + ex[k - 1] + ex[k - 2] + ex[k - 3], 1e-10f));
        float rp1 = __shfl_down(r[0], 1); if (l == 63) rp1 = 0.f;
        float rp2 = __shfl_down(r[1], 1); if (l == 63) rp2 = 0.f;
        float rp3 = __shfl_down(r[2], 1); if (l == 63) rp3 = 0.f;
        float bt[16];
#pragma unroll
        for (int k = 0; k < 13; k++)
            bt[k] = ex[k] * (r[k] + r[k + 1] + r[k + 2] + r[k + 3]);
        bt[13] = ex[13] * (r[13] + r[14] + r[15] + rp1);
        bt[14] = ex[14] * (r[14] + r[15] + rp1 + rp2);
        bt[15] = ex[15] * (r[15] + rp1 + rp2 + rp3);
#pragma unroll
        for (int k = 0; k < 16; k++) betaL[l * 16 + k] = bt[k];
    }
    __syncthreads();
    // ---- ctx partial over chunk ch (rows s0..s0+127), coalesced f16x8 ----
    int wv = tid >> 6, lane = tid & 63;
    int s0 = ch * 128;
    float acc[8] = {0.f};
    const _Float16* ebase = enc16 + ((size_t)(b * SS + s0)) * DN + lane * 8;
    const float* bp = betaL + s0;
#pragma unroll 4
    for (int rr = 0; rr < 16; rr++) {
        int s = wv + rr * 8;
        float bv = bp[s];
        f16x8 ld = *(const f16x8*)(ebase + (size_t)s * DN);
#pragma unroll
        for (int j = 0; j < 8; j++) acc[j] = fmaf(bv, (float)ld[j], acc[j]);
    }
#pragma unroll
    for (int j = 0; j < 8; j++) red[wv][lane * 8 + j] = acc[j];
    __syncthreads();
    float s = 0.f;
#pragma unroll
    for (int wq = 0; wq < 8; wq++) s += red[wq][tid];
    part8[((size_t)(b * 8 + ch)) * DN + tid] = s;
}

// ---------------- fused gates + LSTM: 64 blocks x 512 thr ----------------
__global__ __launch_bounds__(512) void gl_k(const float* __restrict__ part8,
                                            const float* __restrict__ sIn,
                                            const float* __restrict__ WgT,
                                            const int* __restrict__ target, int t,
                                            const float* __restrict__ Lys, const float* __restrict__ Lgsb,
                                            float* __restrict__ c, float* __restrict__ sOut,
                                            float* __restrict__ ctxbuf) {
    __shared__ float xl[BB * KV];
    __shared__ float recL[16][BB];
    int tid = threadIdx.x;
    for (int i = tid; i < BB * HN; i += 512)
        xl[(i >> 8) * KV + (i & (HN - 1))] = sIn[i];
    for (int i = tid; i < BB * DN; i += 512) {
        int bb = i >> 9, d = i & (DN - 1);
        const float* pp = part8 + (size_t)bb * (8 * DN) + d;
        float v = ((pp[0] + pp[DN]) + (pp[2 * DN] + pp[3 * DN])) +
                  ((pp[4 * DN] + pp[5 * DN]) + (pp[6 * DN] + pp[7 * DN]));
        xl[bb * KV + HN + d] = v;
        if (blockIdx.x == 0) ctxbuf[i] = v;
    }
    __syncthreads();
    int wv = tid >> 6, lane = tid & 63;
    int h0 = blockIdx.x * 4;
    int ri0 = wv * 2, ri1 = ri0 + 1;
    const float* w0p = WgT + (size_t)((ri0 >> 2) * HN + h0 + (ri0 & 3)) * KV;
    const float* w1p = WgT + (size_t)((ri1 >> 2) * HN + h0 + (ri1 & 3)) * KV;
    float acc0[BB] = {0.f}, acc1[BB] = {0.f};
#pragma unroll
    for (int j = 0; j < 12; j++) {
        int e = lane + j * 64;
        float w0 = w0p[e], w1 = w1p[e];
#pragma unroll
        for (int b = 0; b < BB; b++) {
            float xv = xl[b * KV + e];
            acc0[b] = fmaf(w0, xv, acc0[b]);
            acc1[b] = fmaf(w1, xv, acc1[b]);
        }
    }
#pragma unroll
    for (int b = 0; b < BB; b++)
#pragma unroll
        for (int off = 32; off > 0; off >>= 1) {
            acc0[b] += __shfl_xor(acc0[b], off);
            acc1[b] += __shfl_xor(acc1[b], off);
        }
    if (lane == 0) {
#pragma unroll
        for (int b = 0; b < BB; b++) {
            recL[ri0][b] = acc0[b];
            recL[ri1][b] = acc1[b];
        }
    }
    __syncthreads();
    if (tid < 64) {
        int b = tid & 15, hh = tid >> 4;
        int h = h0 + hh;
        int tgt = target[b * NSTEPS + t];
        const float* ys = Lys + (size_t)tgt * G4;
        float ri = recL[0 * 4 + hh][b] + ys[h] + Lgsb[h];
        float rf = recL[1 * 4 + hh][b] + ys[h + HN] + Lgsb[h + HN];
        float rg = recL[2 * 4 + hh][b] + ys[h + 2 * HN] + Lgsb[h + 2 * HN];
        float ro = recL[3 * 4 + hh][b] + ys[h + 3 * HN] + Lgsb[h + 3 * HN];
        float cn = fsigm(rf) * c[b * HN + h] + fsigm(ri) * ftanh(rg);
        float sn = fsigm(ro) * ftanh(cn);
        c[b * HN + h] = cn;
        sOut[b * HN + h] = sn;
    }
}

// ---------------- y gate (0..15) + next-step proj (16..79) ----------------
__global__ __launch_bounds__(256) void ypj_k(const float* __restrict__ sNew,
                                             const float* __restrict__ ctxbuf,
                                             const float* __restrict__ WyT, const float* __restrict__ Lgyb,
                                             const float* __restrict__ WpT,
                                             const float* __restrict__ Wsmb, const float* __restrict__ Wscb,
                                             float* __restrict__ yv,
                                             float* __restrict__ smb, float* __restrict__ scb) {
    __shared__ float sl[BB * KV];
    int tid = threadIdx.x;
    for (int i = tid; i < BB * HN; i += 256)
        sl[(i >> 8) * KV + (i & (HN - 1))] = sNew[i];
    for (int i = tid; i < BB * DN; i += 256)
        sl[(i >> 9) * KV + HN + (i & (DN - 1))] = ctxbuf[i];
    __syncthreads();
    int wave = tid >> 6, lane = tid & 63;
    if (blockIdx.x < 16) {
        int h0 = blockIdx.x * 16 + wave * 4;
        for (int q = 0; q < 4; q++) {
            int h = h0 + q;
            const float* wp = WyT + (size_t)h * KV;
            float acc[BB] = {0.f};
#pragma unroll
            for (int j = 0; j < 12; j++) {
                int e = lane + j * 64;
                float wv = wp[e];
#pragma unroll
                for (int b = 0; b < BB; b++) acc[b] = fmaf(wv, sl[b * KV + e], acc[b]);
            }
#pragma unroll
            for (int b = 0; b < BB; b++)
#pragma unroll
                for (int off = 32; off > 0; off >>= 1) acc[b] += __shfl_xor(acc[b], off);
            if (lane == 0) {
#pragma unroll
                for (int b = 0; b < BB; b++) yv[b * HN + h] = ftanh(acc[b] + Lgyb[h]);
            }
        }
    } else {
        int j0 = (blockIdx.x - 16) * 16 + wave * 4;
        for (int q = 0; q < 4; q++) {
            int jc = j0 + q;
            const float* wp = WpT + (size_t)jc * HN;
            float acc[BB] = {0.f};
#pragma unroll
            for (int k = 0; k < 4; k++) {
                int e = lane + k * 64;
                float wv = wp[e];
#pragma unroll
                for (int b = 0; b < BB; b++) acc[b] = fmaf(wv, sl[b * KV + e], acc[b]);
            }
#pragma unroll
            for (int b = 0; b < BB; b++)
#pragma unroll
                for (int off = 32; off > 0; off >>= 1) acc[b] += __shfl_xor(acc[b], off);
            if (lane == 0) {
                if (jc < DN) {
#pragma unroll
                    for (int b = 0; b < BB; b++) smb[b * DN + jc] = acc[b] + Wsmb[jc];
                } else {
                    int jj = jc - DN;
#pragma unroll
                    for (int b = 0; b < BB; b++) scb[b * DN + jj] = acc[b] + Wscb[jj];
                }
            }
        }
    }
}

// ---------------- standalone out projection (final step) ----------------
__global__ __launch_bounds__(256) void out_k(const float* __restrict__ yv,
                                             const float* __restrict__ LyyT, const float* __restrict__ Lyyb,
                                             float* __restrict__ out, int t) {
    __shared__ float shbuf[BB * HN];
    out_proj(blockIdx.x, threadIdx.x, shbuf, yv, LyyT, Lyyb, out, t);
}

extern "C" void kernel_launch(void* const* d_in, const int* in_sizes, int n_in,
                              void* d_out, int out_size, void* d_ws, size_t ws_size,
                              hipStream_t stream) {
    const float* enc  = (const float*)d_in[0];
    const int*   target = (const int*)d_in[1];
    const int*   len  = (const int*)d_in[2];
    const float* noise = (const float*)d_in[3];
    const float* Wsm  = (const float*)d_in[4];
    const float* Wsmb = (const float*)d_in[5];
    const float* WhM  = (const float*)d_in[6];
    const float* vM   = (const float*)d_in[7];
    const float* g    = (const float*)d_in[8];
    const float* rm   = (const float*)d_in[9];
    const float* Wsc  = (const float*)d_in[10];
    const float* Wscb = (const float*)d_in[11];
    const float* WhC  = (const float*)d_in[12];
    const float* vC   = (const float*)d_in[13];
    const float* Lsy  = (const float*)d_in[14];
    const float* Lgy  = (const float*)d_in[15];
    const float* Lgyb = (const float*)d_in[16];
    const float* Lyy  = (const float*)d_in[17];
    const float* Lyyb = (const float*)d_in[18];
    const float* Lys  = (const float*)d_in[19];
    const float* Lss  = (const float*)d_in[20];
    const float* Lgs  = (const float*)d_in[21];
    const float* Lgsb = (const float*)d_in[22];
    float* out = (float*)d_out;

    char* w = (char*)d_ws;
    size_t off = 0;
    auto alloc = [&](size_t bytes) { void* pp = w + off; off += (bytes + 255) & ~(size_t)255; return pp; };
    _Float16* A16   = (_Float16*)alloc((size_t)BB * SS * DN * 2);
    _Float16* WcT   = (_Float16*)alloc((size_t)1024 * 512 * 2);
    _Float16* encMC = (_Float16*)alloc((size_t)BB * SS * 1024 * 2);
    float* WgT  = (float*)alloc((size_t)G4 * KV * 4);
    float* WyT  = (float*)alloc((size_t)HN * KV * 4);
    float* WpT  = (float*)alloc((size_t)G4 * HN * 4);
    float* LyyT = (float*)alloc((size_t)CCLS * HN * 4);
    float* smb   = (float*)alloc(BB * DN * 4);
    float* scb   = (float*)alloc(BB * DN * 4);
    float* pbuf  = (float*)alloc(BB * SS * 4);
    float* ech   = (float*)alloc(BB * SS * 4);
    float* aA    = (float*)alloc(BB * SS * 4);
    float* aBf   = (float*)alloc(BB * SS * 4);
    float* part8 = (float*)alloc((size_t)BB * 8 * DN * 4);
    float* ctxbuf = (float*)alloc((size_t)BB * DN * 4);
    float* sA    = (float*)alloc((size_t)BB * HN * 4);
    float* sB    = (float*)alloc((size_t)BB * HN * 4);
    float* yvb   = (float*)alloc((size_t)BB * HN * 4);
    float* cbuf  = (float*)alloc(BB * HN * 4);
    float* vn    = (float*)alloc(16);
    (void)ws_size; (void)in_sizes; (void)n_in; (void)out_size;

    // ---- preamble (2 launches) ----
    prep_k<<<6241, 256, 0, stream>>>(enc, WhM, WhC, Lss, Lgs, Lsy, Lgy, Wsm, Wsc, Lyy,
                                     vM, g, Wsmb, Wscb,
                                     A16, WcT, WgT, WyT, WpT, LyyT,
                                     aA, sA, cbuf, smb, scb, vn);
    gemm16_k<<<dim3(128, 8), 256, 0, stream>>>(A16, WcT, encMC);

    for (int t = 0; t < NSTEPS; t++) {
        float* ain  = (t % 2 == 0) ? aA : aBf;
        float* aout = (t % 2 == 0) ? aBf : aA;
        float* sIn  = (t % 2 == 0) ? sA : sB;
        float* sOut = (t % 2 == 0) ? sB : sA;
        energy_out_k<<<4159, 256, 0, stream>>>(encMC, smb, scb, vM, vC, vn, rm,
                                               len, noise + (size_t)t * BB * SS, pbuf, ech,
                                               yvb, LyyT, Lyyb, out, t);
        scanctx_k<<<dim3(BB, 8), 512, 0, stream>>>(pbuf, ain, ech, A16, aout, part8);
        gl_k<<<64, 512, 0, stream>>>(part8, sIn, WgT, target, t, Lys, Lgsb, cbuf, sOut, ctxbuf);
        ypj_k<<<80, 256, 0, stream>>>(sOut, ctxbuf, WyT, Lgyb, WpT, Wsmb, Wscb, yvb, smb, scb);
    }
    out_k<<<63, 256, 0, stream>>>(yvb, LyyT, Lyyb, out, NSTEPS - 1);
}